// Round 1
// baseline (447.114 us; speedup 1.0000x reference)
//
#include <hip/hip_runtime.h>
#include <math.h>

#define HH 4096
#define II 4096
#define ROWS_PER_BLOCK 4
#define THREADS 256

// ---------------------------------------------------------------------------
// Kernel 1: 8 fused matvecs. Block b handles 4 consecutive rows of one of the
// 8 matrices {w_i,w_f,w_o,w_z,r_i,r_f,r_o,r_z}. Vector (x for w*, h_prev for
// r*) staged in LDS once per block; one wave per row, float4-coalesced row
// stream, 64-lane shuffle reduction. Writes pre[mat][row] to workspace.
// ---------------------------------------------------------------------------
__global__ __launch_bounds__(THREADS) void slstm_matvec8(
    const float* __restrict__ x, const float* __restrict__ h_prev,
    const float* __restrict__ wi, const float* __restrict__ wf,
    const float* __restrict__ wo, const float* __restrict__ wz,
    const float* __restrict__ ri, const float* __restrict__ rf,
    const float* __restrict__ ro, const float* __restrict__ rz,
    float* __restrict__ pre)
{
    __shared__ float4 vlds[II / 4];            // 16 KiB vector stage

    const int blocks_per_mat = HH / ROWS_PER_BLOCK;   // 1024
    const int mid      = blockIdx.x / blocks_per_mat; // 0..7
    const int row_base = (blockIdx.x % blocks_per_mat) * ROWS_PER_BLOCK;

    const float* mats[8] = {wi, wf, wo, wz, ri, rf, ro, rz};
    const float* mat = mats[mid];
    const float4* vec = (const float4*)((mid < 4) ? x : h_prev);

    const int tid = threadIdx.x;
    #pragma unroll
    for (int k = 0; k < (II / 4) / THREADS; ++k)      // 4 float4 per thread
        vlds[tid + k * THREADS] = vec[tid + k * THREADS];
    __syncthreads();

    const int wave = tid >> 6;
    const int lane = tid & 63;
    const int row  = row_base + wave;
    const float4* mrow = (const float4*)(mat + (size_t)row * II);

    float acc = 0.f;
    #pragma unroll
    for (int j = 0; j < II / 4 / 64; ++j) {           // 16 iterations
        float4 a = mrow[j * 64 + lane];
        float4 v = vlds[j * 64 + lane];
        acc = fmaf(a.x, v.x, acc);
        acc = fmaf(a.y, v.y, acc);
        acc = fmaf(a.z, v.z, acc);
        acc = fmaf(a.w, v.w, acc);
    }

    #pragma unroll
    for (int off = 32; off > 0; off >>= 1)
        acc += __shfl_down(acc, off, 64);

    if (lane == 0)
        pre[mid * HH + row] = acc;
}

// ---------------------------------------------------------------------------
// Kernel 2: element-wise exponential gating. pre layout: [8][H] with
// 0..3 = w_{i,f,o,z}@x, 4..7 = r_{i,f,o,z}@h_prev.
// Output: [h_t | c_t | n_t | m_t], each H floats.
// ---------------------------------------------------------------------------
__global__ void slstm_gates(
    const float* __restrict__ pre,
    const float* __restrict__ c_prev, const float* __restrict__ n_prev,
    const float* __restrict__ m_prev,
    const float* __restrict__ bi, const float* __restrict__ bf,
    const float* __restrict__ bo, const float* __restrict__ bz,
    float* __restrict__ out)
{
    int h = blockIdx.x * blockDim.x + threadIdx.x;
    if (h >= HH) return;

    float it = pre[0 * HH + h] + pre[4 * HH + h] + bi[h];
    float ft = pre[1 * HH + h] + pre[5 * HH + h] + bf[h];
    float ot = pre[2 * HH + h] + pre[6 * HH + h] + bo[h];
    float zt = pre[3 * HH + h] + pre[7 * HH + h] + bz[h];

    float mp = m_prev[h];
    float cp = c_prev[h];
    float np_ = n_prev[h];

    // stable log_sigmoid(ft) = min(ft,0) - log1p(exp(-|ft|))
    float lf = fminf(ft, 0.f) - log1pf(expf(-fabsf(ft)));
    float mt = fmaxf(lf + mp, it);
    float ip = expf(it - mt);
    float fp = expf(lf + mp - mt);
    float ct = fp * cp + ip * tanhf(zt);
    float nt = fp * np_ + ip;
    float sig_o = 1.f / (1.f + expf(-ot));
    float ht = sig_o * tanhf(ct / nt);

    out[0 * HH + h] = ht;
    out[1 * HH + h] = ct;
    out[2 * HH + h] = nt;
    out[3 * HH + h] = mt;
}

extern "C" void kernel_launch(void* const* d_in, const int* in_sizes, int n_in,
                              void* d_out, int out_size, void* d_ws, size_t ws_size,
                              hipStream_t stream)
{
    const float* x      = (const float*)d_in[0];
    const float* h_prev = (const float*)d_in[1];
    const float* c_prev = (const float*)d_in[2];
    const float* n_prev = (const float*)d_in[3];
    const float* m_prev = (const float*)d_in[4];
    const float* wi = (const float*)d_in[5];
    const float* wf = (const float*)d_in[6];
    const float* wo = (const float*)d_in[7];
    const float* wz = (const float*)d_in[8];
    const float* ri = (const float*)d_in[9];
    const float* rf = (const float*)d_in[10];
    const float* ro = (const float*)d_in[11];
    const float* rz = (const float*)d_in[12];
    const float* bi = (const float*)d_in[13];
    const float* bf = (const float*)d_in[14];
    const float* bo = (const float*)d_in[15];
    const float* bz = (const float*)d_in[16];

    float* pre = (float*)d_ws;              // 8 * 4096 * 4 B = 128 KiB
    float* out = (float*)d_out;

    const int grid1 = 8 * (HH / ROWS_PER_BLOCK);   // 8192 blocks
    slstm_matvec8<<<grid1, THREADS, 0, stream>>>(
        x, h_prev, wi, wf, wo, wz, ri, rf, ro, rz, pre);

    slstm_gates<<<(HH + 255) / 256, 256, 0, stream>>>(
        pre, c_prev, n_prev, m_prev, bi, bf, bo, bz, out);
}